// Round 13
// baseline (658.315 us; speedup 1.0000x reference)
//
#include <hip/hip_runtime.h>
#include <hip/hip_bf16.h>

// LoRALinear: out = x @ (W + 2.0*B@A)^T + bias ; M=16384, N=4096, K=4096, R=16.
// Round 13: OCCUPANCY axis. 16-wave (1024-thr) blocks, per-wave output 64x64
// (acc 64 VGPR, half of r12) -> with __launch_bounds__(1024,4) the block runs
// 4 waves/SIMD (vs 2 since r2). TLP does the LDS<->MFMA overlap (m114) that
// three schedule variants (r6/r10/r12, all 474-492us) failed to create at
// 2 waves/SIMD. Frag-linear layout kept (0 conflicts); schedule simplified
// to stage-at-top + 2 k-half clusters + one vmcnt(0)+barrier per K-tile.
// ws layout: [0,134217728) x_frag_bf16 ; [134217728, +33554432) W_frag_bf16.

typedef __attribute__((ext_vector_type(8))) short bf16x8;
typedef __attribute__((ext_vector_type(16))) float f32x16;
typedef __attribute__((ext_vector_type(4))) unsigned short u16x4;

#define M_DIM 16384
#define N_DIM 4096
#define K_DIM 4096
#define NT 64   // K-tiles of BK=64 (4 k16-fragments each)

__device__ __forceinline__ unsigned short f2bf(float f) {
    unsigned int u = __builtin_bit_cast(unsigned int, f);
    unsigned int r = u + 0x7FFFu + ((u >> 16) & 1u);
    return (unsigned short)(r >> 16);
}

__device__ __forceinline__ void async16(const void* g, void* l) {
    __builtin_amdgcn_global_load_lds(
        (const __attribute__((address_space(1))) unsigned int*)g,
        (__attribute__((address_space(3))) unsigned int*)l,
        16, 0, 0);
}

// ---- prep 1: x fp32 -> fragment-linear bf16 (r11, verified) ---------------
__global__ void __launch_bounds__(256) cast_x_kernel(
    const float* __restrict__ x, unsigned short* __restrict__ y) {
    const int total = 512 * 256 * 64;
    int idx = blockIdx.x * 256 + threadIdx.x;
    const int stride = gridDim.x * 256;
    for (; idx < total; idx += stride) {
        const int frag = idx >> 6, l = idx & 63;
        const int m = ((frag >> 8) << 5) + (l & 31);
        const int k = ((frag & 255) << 4) + ((l >> 5) << 3);
        const float4* px = reinterpret_cast<const float4*>(&x[(size_t)m * K_DIM + k]);
        float4 a = px[0], b = px[1];
        unsigned short r[8] = { f2bf(a.x), f2bf(a.y), f2bf(a.z), f2bf(a.w),
                                f2bf(b.x), f2bf(b.y), f2bf(b.z), f2bf(b.w) };
        *reinterpret_cast<bf16x8*>(&y[((size_t)frag << 9) + (l << 3)]) =
            *reinterpret_cast<const bf16x8*>(r);
    }
}

// ---- prep 2: W_eff = W + 2*B@A -> fragment-linear bf16 (r11, verified) ----
__global__ void __launch_bounds__(256) weff_kernel(
    const float* __restrict__ W, const float* __restrict__ lA,
    const float* __restrict__ lB, unsigned short* __restrict__ out) {
    constexpr int K = K_DIM, R = 16;
    constexpr float S = 2.0f;  // 32.0 / 16
    int o = blockIdx.x;
    int t = threadIdx.x;
    float b[R];
#pragma unroll
    for (int r = 0; r < R; ++r) b[r] = lB[o * R + r];
#pragma unroll
    for (int c = 0; c < 4; ++c) {
        int i = c * 1024 + t * 4;
        float4 wv = *reinterpret_cast<const float4*>(&W[o * K + i]);
        float sx = 0.f, sy = 0.f, sz = 0.f, sw = 0.f;
#pragma unroll
        for (int r = 0; r < R; ++r) {
            float4 a = *reinterpret_cast<const float4*>(&lA[r * K + i]);
            sx += b[r] * a.x; sy += b[r] * a.y;
            sz += b[r] * a.z; sw += b[r] * a.w;
        }
        u16x4 ov = { f2bf(wv.x + S * sx), f2bf(wv.y + S * sy),
                     f2bf(wv.z + S * sz), f2bf(wv.w + S * sw) };
        const int frag = (o >> 5) * 256 + (i >> 4);
        const int lane_ = (o & 31) + (((i >> 3) & 1) << 5);
        *reinterpret_cast<u16x4*>(
            &out[((size_t)frag << 9) + (lane_ << 3) + (i & 7)]) = ov;
    }
}

// ---- main GEMM: 256x256 tile, 16-wave, 32x32x16, frag-linear LDS ----------
// LDS per buf: A 32 frags [0,32768) + B 32 frags [32768,65536); x2 dbuf.
// Staging: wave wid moves A frags {wid*2, wid*2+1} and B frags likewise.
#define ASTAGE(t, bsel)                                                       \
    _Pragma("unroll") for (int j = 0; j < 2; ++j) {                           \
        const int g = wid * 2 + j;                                            \
        async16(A + (((size_t)(bm * 8 + (g >> 2)) * 256 + (t) * 4 + (g & 3))  \
                     << 9) + (lane << 3),                                     \
                lds + (bsel) * 65536 + g * 1024 + (lane << 4));               \
    }

#define BSTAGE(t, bsel)                                                       \
    _Pragma("unroll") for (int j = 0; j < 2; ++j) {                           \
        const int g = wid * 2 + j;                                            \
        async16(B + (((size_t)(bn * 8 + (g >> 2)) * 256 + (t) * 4 + (g & 3))  \
                     << 9) + (lane << 3),                                     \
                lds + (bsel) * 65536 + 32768 + g * 1024 + (lane << 4));       \
    }

// per k-half reads: A frags (wm*2+mm, kh*2+kk), B frags (wn*2+nn, kh*2+kk)
#define LDA32(kh, bsel)                                                       \
    _Pragma("unroll") for (int mm = 0; mm < 2; ++mm)                          \
    _Pragma("unroll") for (int kk = 0; kk < 2; ++kk)                          \
        ar[mm * 2 + kk] = *(const bf16x8*)(lds + (bsel) * 65536 +             \
            (((wm * 2 + mm) * 4 + (kh) * 2 + kk) << 10) + (lane << 4));

#define LDB32(kh, bsel)                                                       \
    _Pragma("unroll") for (int nn = 0; nn < 2; ++nn)                          \
    _Pragma("unroll") for (int kk = 0; kk < 2; ++kk)                          \
        br[nn * 2 + kk] = *(const bf16x8*)(lds + (bsel) * 65536 + 32768 +     \
            (((wn * 2 + nn) * 4 + (kh) * 2 + kk) << 10) + (lane << 4));

// one k-half cluster: 8 MFMA (kk2 x mm2 x nn2)
#define MMH()                                                                 \
    __builtin_amdgcn_s_setprio(1);                                            \
    _Pragma("unroll") for (int kk = 0; kk < 2; ++kk)                          \
    _Pragma("unroll") for (int mm = 0; mm < 2; ++mm)                          \
    _Pragma("unroll") for (int nn = 0; nn < 2; ++nn)                          \
        acc[mm][nn] = __builtin_amdgcn_mfma_f32_32x32x16_bf16(                \
            ar[mm * 2 + kk], br[nn * 2 + kk], acc[mm][nn], 0, 0, 0);          \
    __builtin_amdgcn_s_setprio(0)

#define CFENCE() asm volatile("" ::: "memory")

// K-tile: stage t+1 at top (into bo), two k-half read+MFMA clusters from bs,
// one vmcnt(0)+barrier at bottom (drain a full tile after issue).
#define KTILE(t)                                                              \
    {                                                                         \
        const int bs_ = (t) & 1, bo_ = bs_ ^ 1;                               \
        if ((t) + 1 < NT) {                                                   \
            ASTAGE((t) + 1, bo_);                                             \
            BSTAGE((t) + 1, bo_);                                             \
        }                                                                     \
        LDA32(0, bs_);                                                        \
        LDB32(0, bs_);                                                        \
        MMH();                                                                \
        LDA32(1, bs_);                                                        \
        LDB32(1, bs_);                                                        \
        MMH();                                                                \
        if ((t) + 1 < NT) {                                                   \
            asm volatile("s_waitcnt vmcnt(0)" ::: "memory");                  \
            __builtin_amdgcn_s_barrier();                                     \
            CFENCE();                                                         \
        }                                                                     \
    }

__global__ void __launch_bounds__(1024, 4) gemmoc_kernel(
    const unsigned short* __restrict__ A,
    const unsigned short* __restrict__ B,
    const float* __restrict__ bias,
    float* __restrict__ C) {
    __shared__ __align__(1024) char lds[131072];

    const int tid = threadIdx.x;
    const int lane = tid & 63, wid = tid >> 6;
    const int wm = wid >> 2, wn = wid & 3;   // 4 x 4 waves (64 x 64 outputs)
    const int lc = lane & 31, hi = lane >> 5;

    // XCD-aware swizzle: 1024 blocks (divisible by 8)
    const int bid = blockIdx.x;
    const int swz = (bid & 7) * 128 + (bid >> 3);
    const int bm = swz >> 4, bn = swz & 15;  // 64 x 16 tiles

    f32x16 acc[2][2] = {};
    bf16x8 ar[4], br[4];

    // prologue: A(0)+B(0) -> buf0; drain; barrier
    ASTAGE(0, 0);
    BSTAGE(0, 0);
    asm volatile("s_waitcnt vmcnt(0)" ::: "memory");
    __builtin_amdgcn_s_barrier();
    CFENCE();

#pragma unroll 2
    for (int t = 0; t < NT; ++t) {
        KTILE(t);
    }

    // epilogue: 32x32 D layout (r3-verified): col=lane&31,
    // row=(reg&3)+8*(reg>>2)+4*hi
    const int row0 = bm * 256 + wm * 64;
    const int col0 = bn * 256 + wn * 64;
#pragma unroll
    for (int n = 0; n < 2; ++n) {
        const int col = col0 + n * 32 + lc;
        const float bv = bias[col];
#pragma unroll
        for (int m = 0; m < 2; ++m) {
#pragma unroll
            for (int g = 0; g < 4; ++g) {
#pragma unroll
                for (int r = 0; r < 4; ++r) {
                    const int row = row0 + m * 32 + g * 8 + 4 * hi + r;
                    C[(size_t)row * N_DIM + col] = acc[m][n][g * 4 + r] + bv;
                }
            }
        }
    }
}

extern "C" void kernel_launch(void* const* d_in, const int* in_sizes, int n_in,
                              void* d_out, int out_size, void* d_ws, size_t ws_size,
                              hipStream_t stream) {
    const float* x    = (const float*)d_in[0];  // [4,4096,4096]
    const float* W    = (const float*)d_in[1];  // [4096,4096]
    const float* bias = (const float*)d_in[2];  // [4096]
    const float* lA   = (const float*)d_in[3];  // [16,4096]
    const float* lB   = (const float*)d_in[4];  // [4096,16]
    float* out = (float*)d_out;

    unsigned short* xb   = (unsigned short*)d_ws;                       // 134 MB
    unsigned short* weff = (unsigned short*)((char*)d_ws + 134217728);  // 32 MB

    cast_x_kernel<<<4096, 256, 0, stream>>>(x, xb);
    weff_kernel<<<N_DIM, 256, 0, stream>>>(W, lA, lB, weff);
    gemmoc_kernel<<<(M_DIM / 256) * (N_DIM / 256), 1024, 0, stream>>>(
        xb, weff, bias, out);
}

// Round 14
// 593.095 us; speedup vs baseline: 1.1100x; 1.1100x over previous
//
#include <hip/hip_runtime.h>
#include <hip/hip_bf16.h>

// LoRALinear: out = x @ (W + 2.0*B@A)^T + bias ; M=16384, N=4096, K=4096, R=16.
// Round 14: REVERT to round-10 verbatim — the best measured kernel
// (GEMM 474us / 1160 TF, total 593us). Axis ledger (r2..r13): sync-skeleton
// variants 474-515; B-direct -30%; persistence -14%; 32x32/frag-linear
// neutral; occupancy 2->4 waves/SIMD -7%. All four independent mechanisms
// exhausted -> this is the practical HIP-source plateau for this structure.
// ws layout: [0,134217728) x_bf16 ; [134217728, +33554432) W_eff_bf16.

typedef __attribute__((ext_vector_type(8))) short bf16x8;
typedef __attribute__((ext_vector_type(4))) float f32x4;
typedef __attribute__((ext_vector_type(4))) unsigned short u16x4;

#define M_DIM 16384
#define N_DIM 4096
#define K_DIM 4096
#define NT 64   // K-tiles of BK=64

__device__ __forceinline__ unsigned short f2bf(float f) {
    unsigned int u = __builtin_bit_cast(unsigned int, f);
    unsigned int r = u + 0x7FFFu + ((u >> 16) & 1u);
    return (unsigned short)(r >> 16);
}

__device__ __forceinline__ void async16(const void* g, void* l) {
    __builtin_amdgcn_global_load_lds(
        (const __attribute__((address_space(1))) unsigned int*)g,
        (__attribute__((address_space(3))) unsigned int*)l,
        16, 0, 0);
}

// ---------------- prep kernel 1: x fp32 -> bf16 ----------------
__global__ void __launch_bounds__(256) cast_x_kernel(
    const float4* __restrict__ x, u16x4* __restrict__ y, int n4) {
    int i = blockIdx.x * blockDim.x + threadIdx.x;
    int stride = gridDim.x * blockDim.x;
    for (; i < n4; i += stride) {
        float4 v = x[i];
        u16x4 o = { f2bf(v.x), f2bf(v.y), f2bf(v.z), f2bf(v.w) };
        y[i] = o;
    }
}

// ---------------- prep kernel 2: W_eff = W + 2*B@A -> bf16 ----------------
__global__ void __launch_bounds__(256) weff_kernel(
    const float* __restrict__ W, const float* __restrict__ lA,
    const float* __restrict__ lB, unsigned short* __restrict__ out) {
    constexpr int K = K_DIM, R = 16;
    constexpr float S = 2.0f;  // 32.0 / 16
    int o = blockIdx.x;
    int t = threadIdx.x;
    float b[R];
#pragma unroll
    for (int r = 0; r < R; ++r) b[r] = lB[o * R + r];
#pragma unroll
    for (int c = 0; c < 4; ++c) {
        int i = c * 1024 + t * 4;
        float4 wv = *reinterpret_cast<const float4*>(&W[o * K + i]);
        float sx = 0.f, sy = 0.f, sz = 0.f, sw = 0.f;
#pragma unroll
        for (int r = 0; r < R; ++r) {
            float4 a = *reinterpret_cast<const float4*>(&lA[r * K + i]);
            sx += b[r] * a.x; sy += b[r] * a.y;
            sz += b[r] * a.z; sw += b[r] * a.w;
        }
        u16x4 ov = { f2bf(wv.x + S * sx), f2bf(wv.y + S * sy),
                     f2bf(wv.z + S * sz), f2bf(wv.w + S * sw) };
        *reinterpret_cast<u16x4*>(&out[o * K + i]) = ov;
    }
}

// ---------------- main GEMM: 256x256 tile, 8-wave, 16x16x32 MFMA ----------------
// LDS (x2 dbuf): A tile 256x64 bf16 [0,32768) + B tile [32768,65536) per buf,
// 128B rows, XOR-swizzled: phys = row*128 + (colbyte ^ ((row&7)<<4)).
#define STAGE(G, h, tt, bsel, moff)                                           \
    do {                                                                      \
        const unsigned short* g0 = (G) +                                      \
            (size_t)((h) * 128 + wid * 16 + rc) * K_DIM + (tt) * 64 + cc * 8; \
        char* l0 = lds + (bsel) * 65536 + (moff) + (h) * 16384 + wid * 2048;  \
        async16(g0, l0);                                                      \
        async16(g0 + 8 * K_DIM, l0 + 1024);                                   \
    } while (0)

// single-ks fragment reads (measured 0 bank conflicts)
#define LDA_KS(dst, mh, ks, bsel)                                             \
    _Pragma("unroll") for (int mm = 0; mm < 4; ++mm)                          \
        dst[mm] = *(const bf16x8*)(lds + (bsel) * 65536 +                     \
            ((aBase + ((mh) * 4 + mm) * 2048) ^ ((ks) << 6)));

#define LDB_KS(ks, bsel)                                                      \
    _Pragma("unroll") for (int nn = 0; nn < 4; ++nn)                          \
        br[nn][ks] = *(const bf16x8*)(lds + (bsel) * 65536 +                  \
            ((bBase + nn * 2048) ^ ((ks) << 6)));

// one cluster: 16 MFMA, fixed ks, A-set src (4 frags), all 4 n-frags
#define MMQ_KS(src, mh, ks)                                                   \
    __builtin_amdgcn_s_setprio(1);                                            \
    _Pragma("unroll") for (int mm = 0; mm < 4; ++mm)                          \
    _Pragma("unroll") for (int nn = 0; nn < 4; ++nn)                          \
        acc[(mh) * 4 + mm][nn] = __builtin_amdgcn_mfma_f32_16x16x32_bf16(     \
            src[mm], br[nn][ks], acc[(mh) * 4 + mm][nn], 0, 0, 0);            \
    __builtin_amdgcn_s_setprio(0)

#define CFENCE() asm volatile("" ::: "memory")
#define WAIT_LGKM(n)                                                          \
    asm volatile("s_waitcnt lgkmcnt(" #n ")" ::: "memory");                   \
    __builtin_amdgcn_sched_barrier(0)

// K-tile: clusters pipelined one read-group ahead.
// lgkm queue walk (per wave): G0(8) G1(4) -> wait(4)=G0 done; G2(8) ->
// wait(8)=G1 done; G3(4) -> wait(4)=G2 done; wait(0)=G3 done.
#define KTILE(t)                                                              \
    {                                                                         \
        const int bs_ = (t) & 1, bo_ = bs_ ^ 1;                               \
        LDA_KS(arE, 0, 0, bs_);            /* G0a: 4 */                       \
        LDB_KS(0, bs_);                    /* G0b: 4 */                       \
        if ((t) + 1 < NT) STAGE(Ag, 0, (t) + 1, bo_, 0);                      \
        LDA_KS(arO, 1, 0, bs_);            /* G1: 4 */                        \
        WAIT_LGKM(4);                                                         \
        MMQ_KS(arE, 0, 0);                                                    \
        if ((t) + 1 < NT) STAGE(Ag, 1, (t) + 1, bo_, 0);                      \
        LDA_KS(arE, 0, 1, bs_);            /* G2a: 4 (arE WAR after M0) */    \
        LDB_KS(1, bs_);                    /* G2b: 4 */                       \
        WAIT_LGKM(8);                                                         \
        MMQ_KS(arO, 1, 0);                                                    \
        LDA_KS(arO, 1, 1, bs_);            /* G3: 4 */                        \
        WAIT_LGKM(4);                                                         \
        MMQ_KS(arE, 0, 1);                                                    \
        CFENCE();                                                             \
        __builtin_amdgcn_s_barrier();  /* all B reads retired (G2 waited) */  \
        CFENCE();                                                             \
        if ((t) + 2 < NT) STAGE(Bg, 0, (t) + 2, bs_, 32768);                  \
        WAIT_LGKM(0);                                                         \
        MMQ_KS(arO, 1, 1);                                                    \
        if ((t) + 2 < NT) STAGE(Bg, 1, (t) + 2, bs_, 32768);                  \
        if ((t) < NT - 2) {                                                   \
            asm volatile("s_waitcnt vmcnt(4)" ::: "memory");                  \
        } else {                                                              \
            asm volatile("s_waitcnt vmcnt(0)" ::: "memory");                  \
        }                                                                     \
        __builtin_amdgcn_s_barrier();                                         \
        CFENCE();                                                             \
    }

__global__ void __launch_bounds__(512, 2) gemmks_kernel(
    const unsigned short* __restrict__ A,
    const unsigned short* __restrict__ B,
    const float* __restrict__ bias,
    float* __restrict__ C) {
    __shared__ __align__(1024) char lds[131072];

    const int tid = threadIdx.x;
    const int lane = tid & 63, wid = tid >> 6;
    const int wm = wid >> 2, wn = wid & 3;   // 2 x 4 waves
    const int lr = lane & 15, lg = lane >> 4;

    // XCD-aware swizzle: 1024 blocks (divisible by 8)
    const int bid = blockIdx.x;
    const int swz = (bid & 7) * 128 + (bid >> 3);
    const int bm = swz >> 4, bn = swz & 15;  // 64 x 16 tiles

    const unsigned short* Ag = A + (size_t)bm * 256 * K_DIM;
    const unsigned short* Bg = B + (size_t)bn * 256 * K_DIM;

    // staging lane pre-swizzle (inverse of the read XOR)
    const int lam = lane ^ (lane >> 3);
    const int rc = lam >> 3, cc = lam & 7;

    // read-side swizzled bases
    const int kx0 = (lg * 16) ^ ((lr & 7) << 4);
    const int aBase = (wm * 128 + lr) * 128 + kx0;
    const int bBase = 32768 + (wn * 64 + lr) * 128 + kx0;

    f32x4 acc[8][4] = {};
    bf16x8 arE[4], arO[4], br[4][2];

    // prologue: B(0), A(0) -> buf0 ; B(1) -> buf1 ; vmcnt(4) retires B(0)+A(0)
    STAGE(Bg, 0, 0, 0, 32768);
    STAGE(Bg, 1, 0, 0, 32768);
    STAGE(Ag, 0, 0, 0, 0);
    STAGE(Ag, 1, 0, 0, 0);
    STAGE(Bg, 0, 1, 1, 32768);
    STAGE(Bg, 1, 1, 1, 32768);
    asm volatile("s_waitcnt vmcnt(4)" ::: "memory");
    __builtin_amdgcn_s_barrier();
    CFENCE();

#pragma unroll 2
    for (int t = 0; t < NT; ++t) {
        KTILE(t);
    }

    // epilogue: D col = lane&15, row = (lane>>4)*4 + r (verified m89/m91)
    const int row0 = bm * 256 + wm * 128;
    const int col0 = bn * 256 + wn * 64;
#pragma unroll
    for (int n = 0; n < 4; ++n) {
        const int col = col0 + n * 16 + lr;
        const float bv = bias[col];
#pragma unroll
        for (int m = 0; m < 8; ++m) {
            const int r0 = row0 + m * 16 + lg * 4;
#pragma unroll
            for (int r = 0; r < 4; ++r)
                C[(size_t)(r0 + r) * N_DIM + col] = acc[m][n][r] + bv;
        }
    }
}

extern "C" void kernel_launch(void* const* d_in, const int* in_sizes, int n_in,
                              void* d_out, int out_size, void* d_ws, size_t ws_size,
                              hipStream_t stream) {
    const float* x    = (const float*)d_in[0];  // [4,4096,4096]
    const float* W    = (const float*)d_in[1];  // [4096,4096]
    const float* bias = (const float*)d_in[2];  // [4096]
    const float* lA   = (const float*)d_in[3];  // [16,4096]
    const float* lB   = (const float*)d_in[4];  // [4096,16]
    float* out = (float*)d_out;

    unsigned short* xb   = (unsigned short*)d_ws;                       // 134 MB
    unsigned short* weff = (unsigned short*)((char*)d_ws + 134217728);  // 32 MB

    cast_x_kernel<<<2048, 256, 0, stream>>>((const float4*)x, (u16x4*)xb,
                                            M_DIM * K_DIM / 4);
    weff_kernel<<<N_DIM, 256, 0, stream>>>(W, lA, lB, weff);
    gemmks_kernel<<<(M_DIM / 256) * (N_DIM / 256), 512, 0, stream>>>(
        xb, weff, bias, out);
}